// Round 4
// baseline (1461.866 us; speedup 1.0000x reference)
//
#include <hip/hip_runtime.h>
#include <hip/hip_bf16.h>

#define NN 100000
#define EE 640000
#define DD 128
#define RR 8
#define K_TOT (NN * RR)          // 800000 CSR keys: key = r*NN + dst (relation-major)
#define NSB 196                  // ceil(K_TOT / 4096) scan blocks
#define CAP 512                  // per-(tile,round) staged edge cap (global fallback)

typedef __attribute__((ext_vector_type(8))) short short8;
typedef __attribute__((ext_vector_type(4))) float floatx4;
typedef __attribute__((ext_vector_type(4))) unsigned int uint4v;

__device__ __forceinline__ unsigned short f2bf(float f) {
  unsigned int u = __float_as_uint(f);
  u += 0x7FFFu + ((u >> 16) & 1u);   // RNE
  return (unsigned short)(u >> 16);
}
__device__ __forceinline__ unsigned int pk2bf(float a, float b) {
  __hip_bfloat162 h = __float22bfloat162_rn(make_float2(a, b));
  unsigned int u;
  __builtin_memcpy(&u, &h, 4);
  return u;                          // low16 = a, high16 = b
}

// ---------------------------------------------------------------------------
// x (fp32 [NN][128]) -> Xbs split-packed bf16: dword l of row = (col l | col l+64 <<16)
// ---------------------------------------------------------------------------
__global__ __launch_bounds__(256) void xb_prep(
    const float* __restrict__ x, unsigned int* __restrict__ xbs)
{
  int g = blockIdx.x * 256 + threadIdx.x;        // 0..799999
  int row = g >> 3, seg = g & 7;
  const float4* lo4 = (const float4*)(x + (size_t)row * 128 + seg * 8);
  const float4* hi4 = (const float4*)(x + (size_t)row * 128 + 64 + seg * 8);
  float4 a0 = lo4[0], a1 = lo4[1], b0 = hi4[0], b1 = hi4[1];
  uint4v o0, o1;
  o0[0] = pk2bf(a0.x, b0.x); o0[1] = pk2bf(a0.y, b0.y);
  o0[2] = pk2bf(a0.z, b0.z); o0[3] = pk2bf(a0.w, b0.w);
  o1[0] = pk2bf(a1.x, b1.x); o1[1] = pk2bf(a1.y, b1.y);
  o1[2] = pk2bf(a1.z, b1.z); o1[3] = pk2bf(a1.w, b1.w);
  uint4v* dst = (uint4v*)(xbs + (size_t)row * 64 + seg * 8);
  dst[0] = o0; dst[1] = o1;
}

// ---------------------------------------------------------------------------
// Weights: Wt[r][n][k] = bf16(W_r[k][n]); r=8 is root_w.
// ---------------------------------------------------------------------------
__global__ __launch_bounds__(256) void w_prep(
    const float* __restrict__ relw, const float* __restrict__ rootw,
    unsigned short* __restrict__ wt)
{
  int id = blockIdx.x * 256 + threadIdx.x;       // [0, 9*128*128)
  int r = id >> 14, rem = id & 16383;
  int n = rem >> 7, k = rem & 127;
  float v = (r < RR) ? relw[((size_t)r * DD + k) * DD + n] : rootw[(size_t)k * DD + n];
  wt[id] = f2bf(v);
}

// ---------------------------------------------------------------------------
// CSR build (relation-major): count -> scan(a,b,c) -> place.  key = r*NN + dst
// ---------------------------------------------------------------------------
__global__ __launch_bounds__(256) void count_kernel(
    const int* __restrict__ ei, const int* __restrict__ et, int* __restrict__ cnt)
{
  int e = blockIdx.x * 256 + threadIdx.x;
  atomicAdd(&cnt[et[e] * NN + ei[EE + e]], 1);
}

__global__ __launch_bounds__(256) void scan_a(
    const int4* __restrict__ cnt4, int* __restrict__ bsum)
{
  int t = threadIdx.x;
  int s = 0;
#pragma unroll
  for (int i = 0; i < 4; ++i) {
    int idx = blockIdx.x * 1024 + i * 256 + t;
    if (idx < K_TOT / 4) { int4 v = cnt4[idx]; s += v.x + v.y + v.z + v.w; }
  }
  __shared__ int wsum[4];
  for (int d = 32; d; d >>= 1) s += __shfl_xor(s, d, 64);
  if ((t & 63) == 0) wsum[t >> 6] = s;
  __syncthreads();
  if (t == 0) bsum[blockIdx.x] = wsum[0] + wsum[1] + wsum[2] + wsum[3];
}

__global__ void scan_b(const int* __restrict__ bsum, int* __restrict__ bbase)
{
  int lane = threadIdx.x;                         // 64 threads
  int v[4]; int s = 0;
#pragma unroll
  for (int i = 0; i < 4; ++i) {
    int idx = lane * 4 + i;
    v[i] = (idx < NSB) ? bsum[idx] : 0; s += v[i];
  }
  int inc = s;
  for (int d = 1; d < 64; d <<= 1) {
    int o = __shfl_up(inc, d, 64);
    if (lane >= d) inc += o;
  }
  int running = inc - s;
#pragma unroll
  for (int i = 0; i < 4; ++i) {
    int idx = lane * 4 + i;
    if (idx < NSB) { bbase[idx] = running; running += v[i]; }
  }
}

__global__ __launch_bounds__(256) void scan_c(
    const int* __restrict__ cnt, const int* __restrict__ bbase,
    int* __restrict__ rowptr, int* __restrict__ rowfill)
{
  int t = threadIdx.x;
  int base = blockIdx.x * 4096 + t * 16;
  int v[16]; int s = 0;
#pragma unroll
  for (int i = 0; i < 16; ++i) {
    int idx = base + i;
    v[i] = (idx < K_TOT) ? cnt[idx] : 0; s += v[i];
  }
  int lane = t & 63, wid = t >> 6;
  int inc = s;
  for (int d = 1; d < 64; d <<= 1) {
    int o = __shfl_up(inc, d, 64);
    if (lane >= d) inc += o;
  }
  __shared__ int wsum[4];
  if (lane == 63) wsum[wid] = inc;
  __syncthreads();
  int wb = 0;
  for (int w = 0; w < wid; ++w) wb += wsum[w];
  int running = bbase[blockIdx.x] + wb + (inc - s);
#pragma unroll
  for (int i = 0; i < 16; ++i) {
    int idx = base + i;
    if (idx < K_TOT) { rowptr[idx] = running; rowfill[idx] = running; running += v[i]; }
  }
  if (blockIdx.x == 0 && t == 0) rowptr[K_TOT] = EE;
}

// esd[slot] = (dst&63)<<17 | src   (src < 2^17, dstl = dst mod 64)
__global__ __launch_bounds__(256) void place_kernel(
    const int* __restrict__ ei, const int* __restrict__ et,
    int* __restrict__ rowfill, int* __restrict__ esd)
{
  int e = blockIdx.x * 256 + threadIdx.x;
  int src = ei[e], dst = ei[EE + e];
  int slot = atomicAdd(&rowfill[et[e] * NN + dst], 1);
  esd[slot] = ((dst & 63) << 17) | src;
}

// ---------------------------------------------------------------------------
// Fused RGCN layer, 64-dst-row tiles, edge-parallel LDS-f32 aggregation.
// Per round r<8: zero Af -> wave-parallel edges (ds_add_f32, conflict-free via
// 4*(row&15) dword rotation) -> f32 fragments scaled+cvt in regs -> MFMA.
// Round 8 = root (Af = Xbs[dst] direct). Epilogue: +bias, relu;
// mid layer stores split-packed bf16, final stores fp32.
// ---------------------------------------------------------------------------
__global__ __launch_bounds__(256, 2) void fused_layer(
    const unsigned int* __restrict__ Xbs,    // [NN][64] split-packed bf16
    const int* __restrict__ rowptr,          // [K_TOT+1]
    const int* __restrict__ esd,             // [EE]
    const unsigned short* __restrict__ Wt,   // [9][128][128] bf16 [r][n][k]
    const float* __restrict__ bias,          // [128]
    void* __restrict__ outp, int out_bf16)
{
  __shared__ float Af[64 * 128];             // 32 KB f32 accumulator (rotated)
  __shared__ unsigned int WsU[128 * 64];     // 32 KB bf16 weights (rotated)
  __shared__ float sclL[8 * 64];             // 1/max(cnt,1)
  __shared__ int eL[CAP];
  __shared__ int ebA[8], eeA[8];

  const int tid = threadIdx.x;
  const int row0 = blockIdx.x * 64;
  const int wave = tid >> 6, lane = tid & 63;
  const int quad = lane >> 4, mr = lane & 15;

  // ---- initial staging: scales + edge-range bounds ----
  for (int t = tid; t < 512; t += 256) {
    int r = t >> 6, row = t & 63, grow = row0 + row;
    float s = 1.f;
    if (grow < NN) {
      int key = r * NN + grow;
      s = 1.0f / (float)max(rowptr[key + 1] - rowptr[key], 1);
    }
    sclL[t] = s;
  }
  if (tid < 8) {
    int hi = min(row0 + 64, NN);
    ebA[tid] = rowptr[tid * NN + row0];
    eeA[tid] = rowptr[tid * NN + hi];
  }

  floatx4 acc[8];
#pragma unroll
  for (int ni = 0; ni < 8; ++ni) acc[ni] = (floatx4){0.f, 0.f, 0.f, 0.f};
  __syncthreads();

  for (int r = 0; r < 9; ++r) {
    // ---- phase 1: stage Ws(r) (rotated by 4*(n&15) dwords) ----
    {
      int n = tid >> 1, half = tid & 1;
      const uint4v* wsrc = (const uint4v*)(Wt + ((size_t)r * 128 + n) * 128);
      int rot = 4 * (n & 15);
#pragma unroll
      for (int k = 0; k < 8; ++k) {
        uint4v v = wsrc[half * 8 + k];
        int pos = (half * 32 + k * 4 + rot) & 63;
        *(uint4v*)&WsU[n * 64 + pos] = v;
      }
    }
    if (r < RR) {
      // zero Af + stage edge list
      {
        floatx4 z = {0.f, 0.f, 0.f, 0.f};
#pragma unroll
        for (int k = 0; k < 8; ++k) *(floatx4*)&Af[tid * 32 + k * 4] = z;
      }
      int eb = ebA[r], len = eeA[r] - ebA[r];
      int cap = min(len, CAP);
      for (int i = tid; i < cap; i += 256) eL[i] = esd[eb + i];
      __syncthreads();

      // ---- phase 2: edge-parallel adds (1 edge per wave-iter) ----
      int wb = (len * wave) >> 2;
      int we = (len * (wave + 1)) >> 2;
      int i = wb;
#define GETE(idx) __builtin_amdgcn_readfirstlane((idx) < CAP ? eL[idx] : esd[eb + (idx)])
#define ADDX(ed, u) { \
        int dl_ = (ed) >> 17; \
        float lo_ = __uint_as_float((u) << 16); \
        float hi_ = __uint_as_float((u) & 0xFFFF0000u); \
        int rot_ = 4 * (dl_ & 15); \
        atomicAdd(&Af[dl_ * 128 + lane + rot_], lo_); \
        atomicAdd(&Af[dl_ * 128 + ((lane + 64 + rot_) & 127)], hi_); }
      for (; i + 4 <= we; i += 4) {
        int d0 = GETE(i), d1 = GETE(i + 1), d2 = GETE(i + 2), d3 = GETE(i + 3);
        unsigned u0 = Xbs[(size_t)(d0 & 0x1FFFF) * 64 + lane];
        unsigned u1 = Xbs[(size_t)(d1 & 0x1FFFF) * 64 + lane];
        unsigned u2 = Xbs[(size_t)(d2 & 0x1FFFF) * 64 + lane];
        unsigned u3 = Xbs[(size_t)(d3 & 0x1FFFF) * 64 + lane];
        ADDX(d0, u0); ADDX(d1, u1); ADDX(d2, u2); ADDX(d3, u3);
      }
      for (; i < we; ++i) {
        int d = GETE(i);
        unsigned u = Xbs[(size_t)(d & 0x1FFFF) * 64 + lane];
        ADDX(d, u);
      }
#undef GETE
#undef ADDX
      __syncthreads();
    } else {
      // ---- root: Af = Xbs[row0+row] (rotated) ----
      int row = tid >> 2, q4 = tid & 3, grow = row0 + row;
      int rot = 4 * (row & 15);
      const uint4v* xsrc = (const uint4v*)(Xbs + (size_t)grow * 64);
#pragma unroll
      for (int k = 0; k < 4; ++k) {
        uint4v v = (grow < NN) ? xsrc[q4 * 4 + k] : (uint4v){0u, 0u, 0u, 0u};
        floatx4 flo, fhi;
#pragma unroll
        for (int j = 0; j < 4; ++j) {
          flo[j] = __uint_as_float(v[j] << 16);
          fhi[j] = __uint_as_float(v[j] & 0xFFFF0000u);
        }
        int c0 = q4 * 16 + k * 4;
        *(floatx4*)&Af[row * 128 + ((c0 + rot) & 127)] = flo;
        *(floatx4*)&Af[row * 128 + ((c0 + 64 + rot) & 127)] = fhi;
      }
      __syncthreads();
    }

    // ---- phase 3: fragments + MFMA (wave handles rows [wave*16,+16), all 128 cols) ----
    {
      float s = (r < RR) ? sclL[r * 64 + wave * 16 + mr] : 1.0f;
      int arow = wave * 16 + mr;
#pragma unroll
      for (int ks = 0; ks < 4; ++ks) {
        int base = ks * 32 + quad * 8 + 4 * mr;
        floatx4 f0 = *(floatx4*)&Af[arow * 128 + (base & 127)];
        floatx4 f1 = *(floatx4*)&Af[arow * 128 + ((base + 4) & 127)];
        uint4v au;
        au[0] = pk2bf(f0[0] * s, f0[1] * s);
        au[1] = pk2bf(f0[2] * s, f0[3] * s);
        au[2] = pk2bf(f1[0] * s, f1[1] * s);
        au[3] = pk2bf(f1[2] * s, f1[3] * s);
        short8 a;
        __builtin_memcpy(&a, &au, 16);
        int wk = (ks * 16 + quad * 4 + 4 * mr) & 63;
#pragma unroll
        for (int ni = 0; ni < 8; ++ni) {
          short8 b = *(short8*)&WsU[(ni * 16 + mr) * 64 + wk];
          acc[ni] = __builtin_amdgcn_mfma_f32_16x16x32_bf16(a, b, acc[ni], 0, 0, 0);
        }
      }
    }
    __syncthreads();
  }

  // ---- epilogue: C/D col=lane&15(=mr), row=quad*4+reg ----
  if (out_bf16) {
    // stage f32 results to Af (natural layout), then split-pack to bf16 global
#pragma unroll
    for (int ni = 0; ni < 8; ++ni) {
      int col = ni * 16 + mr;
      float bv = bias[col];
#pragma unroll
      for (int rg = 0; rg < 4; ++rg) {
        int lr = wave * 16 + quad * 4 + rg;
        Af[lr * 128 + col] = fmaxf(acc[ni][rg] + bv, 0.f);
      }
    }
    __syncthreads();
    int lr = tid >> 2, q4 = tid & 3, grow = row0 + lr;
    if (grow < NN) {
      unsigned int* h1u = (unsigned int*)outp;
#pragma unroll
      for (int k = 0; k < 4; ++k) {
        int l = q4 * 16 + k * 4;
        floatx4 lo = *(floatx4*)&Af[lr * 128 + l];
        floatx4 hi = *(floatx4*)&Af[lr * 128 + l + 64];
        uint4v o;
        o[0] = pk2bf(lo[0], hi[0]); o[1] = pk2bf(lo[1], hi[1]);
        o[2] = pk2bf(lo[2], hi[2]); o[3] = pk2bf(lo[3], hi[3]);
        *(uint4v*)&h1u[(size_t)grow * 64 + l] = o;
      }
    }
  } else {
    float* out = (float*)outp;
#pragma unroll
    for (int ni = 0; ni < 8; ++ni) {
      int col = ni * 16 + mr;
      float bv = bias[col];
#pragma unroll
      for (int rg = 0; rg < 4; ++rg) {
        int rr = row0 + wave * 16 + quad * 4 + rg;
        if (rr < NN) out[(size_t)rr * 128 + col] = fmaxf(acc[ni][rg] + bv, 0.f);
      }
    }
  }
}

// ---------------------------------------------------------------------------
extern "C" void kernel_launch(void* const* d_in, const int* in_sizes, int n_in,
                              void* d_out, int out_size, void* d_ws, size_t ws_size,
                              hipStream_t stream) {
  const float* x       = (const float*)d_in[0];
  const int*   ei      = (const int*)d_in[1];
  const int*   et      = (const int*)d_in[2];
  const float* rel_w1  = (const float*)d_in[3];
  const float* root_w1 = (const float*)d_in[4];
  const float* b1      = (const float*)d_in[5];
  const float* rel_w2  = (const float*)d_in[6];
  const float* root_w2 = (const float*)d_in[7];
  const float* b2      = (const float*)d_in[8];
  float* out = (float*)d_out;

  char* ws = (char*)d_ws;
  size_t off = 0;
  auto alloc = [&](size_t bytes) { char* p = ws + off; off = (off + bytes + 255) & ~(size_t)255; return p; };
  unsigned int*   Xbs     = (unsigned int*)alloc((size_t)NN * 64 * 4);         // 25.6 MB
  unsigned int*   h1      = (unsigned int*)alloc((size_t)NN * 64 * 4);         // 25.6 MB
  unsigned short* Wt1     = (unsigned short*)alloc((size_t)9 * DD * DD * 2);
  unsigned short* Wt2     = (unsigned short*)alloc((size_t)9 * DD * DD * 2);
  int*            cnt32   = (int*)alloc((size_t)K_TOT * 4);
  int*            rowptr  = (int*)alloc((size_t)(K_TOT + 1) * 4);
  int*            rowfill = (int*)alloc((size_t)K_TOT * 4);
  int*            esd     = (int*)alloc((size_t)EE * 4);
  int*            bsum    = (int*)alloc((size_t)NSB * 4);
  int*            bbase   = (int*)alloc((size_t)NSB * 4);

  hipMemsetAsync(cnt32, 0, (size_t)K_TOT * 4, stream);

  xb_prep<<<3125, 256, 0, stream>>>(x, Xbs);
  w_prep<<<(9 * DD * DD) / 256, 256, 0, stream>>>(rel_w1, root_w1, Wt1);
  w_prep<<<(9 * DD * DD) / 256, 256, 0, stream>>>(rel_w2, root_w2, Wt2);

  count_kernel<<<EE / 256, 256, 0, stream>>>(ei, et, cnt32);
  scan_a<<<NSB, 256, 0, stream>>>((const int4*)cnt32, bsum);
  scan_b<<<1, 64, 0, stream>>>(bsum, bbase);
  scan_c<<<NSB, 256, 0, stream>>>(cnt32, bbase, rowptr, rowfill);
  place_kernel<<<EE / 256, 256, 0, stream>>>(ei, et, rowfill, esd);

  const int GRID = (NN + 63) / 64;   // 1563 tiles of 64 dst rows
  fused_layer<<<GRID, 256, 0, stream>>>(Xbs, rowptr, esd, Wt1, b1, h1, 1);
  fused_layer<<<GRID, 256, 0, stream>>>(h1, rowptr, esd, Wt2, b2, out, 0);
}

// Round 5
// 504.068 us; speedup vs baseline: 2.9001x; 2.9001x over previous
//
#include <hip/hip_runtime.h>
#include <hip/hip_bf16.h>

#define NN 100000
#define EE 640000
#define DD 128
#define RR 8
#define NSB 25            // ceil(100000/4096) scan blocks

typedef __attribute__((ext_vector_type(8))) short short8;
typedef __attribute__((ext_vector_type(4))) float floatx4;
typedef __attribute__((ext_vector_type(4))) unsigned int uint4v;

__device__ __forceinline__ unsigned short f2bf(float f) {
  unsigned int u = __float_as_uint(f);
  u += 0x7FFFu + ((u >> 16) & 1u);   // RNE
  return (unsigned short)(u >> 16);
}
__device__ __forceinline__ unsigned int pk2bf(float a, float b) {
  __hip_bfloat162 h = __float22bfloat162_rn(make_float2(a, b));
  unsigned int u;
  __builtin_memcpy(&u, &h, 4);
  return u;                          // low16 = a, high16 = b
}
__device__ __forceinline__ float bflo(unsigned int u) { return __uint_as_float(u << 16); }
__device__ __forceinline__ float bfhi(unsigned int u) { return __uint_as_float(u & 0xFFFF0000u); }

// ---------------------------------------------------------------------------
// x (fp32 [NN][128]) -> Xb (bf16 std rows, as uints: uint j = cols 2j|2j+1<<16)
// ---------------------------------------------------------------------------
__global__ __launch_bounds__(256) void xb_prep(
    const float* __restrict__ x, unsigned int* __restrict__ xb)
{
  int g = blockIdx.x * 256 + threadIdx.x;        // 1,600,000 threads? no: 800000
  int v = g >> 4, seg = g & 15;                  // 16 threads/row, 8 cols each
  const float4* s4 = (const float4*)(x + (size_t)v * 128 + seg * 8);
  float4 a = s4[0], b = s4[1];
  uint4v o;
  o[0] = pk2bf(a.x, a.y); o[1] = pk2bf(a.z, a.w);
  o[2] = pk2bf(b.x, b.y); o[3] = pk2bf(b.z, b.w);
  *(uint4v*)(xb + (size_t)v * 64 + seg * 4) = o;
}

// ---------------------------------------------------------------------------
// Weights: Wt[r][n][k] = bf16(W_r[k][n]); r=8 is root_w.
// ---------------------------------------------------------------------------
__global__ __launch_bounds__(256) void w_prep(
    const float* __restrict__ relw, const float* __restrict__ rootw,
    unsigned short* __restrict__ wt)
{
  int id = blockIdx.x * 256 + threadIdx.x;       // [0, 9*128*128)
  int r = id >> 14, rem = id & 16383;
  int n = rem >> 7, k = rem & 127;
  float v = (r < RR) ? relw[((size_t)r * DD + k) * DD + n] : rootw[(size_t)k * DD + n];
  wt[id] = f2bf(v);
}

// ---------------------------------------------------------------------------
// dst-major CSR build: count -> scan(a,b,c) -> place (rec = src|r<<17, scale)
// ---------------------------------------------------------------------------
__global__ __launch_bounds__(256) void count2(
    const int* __restrict__ ei, const int* __restrict__ et,
    int* __restrict__ cntd, int* __restrict__ cntdr)
{
  int e = blockIdx.x * 256 + threadIdx.x;
  int dst = ei[EE + e];
  atomicAdd(&cntd[dst], 1);
  atomicAdd(&cntdr[dst * RR + et[e]], 1);
}

__global__ __launch_bounds__(256) void scan_a(
    const int4* __restrict__ cnt4, int* __restrict__ bsum)
{
  int t = threadIdx.x;
  int s = 0;
#pragma unroll
  for (int i = 0; i < 4; ++i) {
    int idx = blockIdx.x * 1024 + i * 256 + t;
    if (idx < NN / 4) { int4 v = cnt4[idx]; s += v.x + v.y + v.z + v.w; }
  }
  __shared__ int wsum[4];
  for (int d = 32; d; d >>= 1) s += __shfl_xor(s, d, 64);
  if ((t & 63) == 0) wsum[t >> 6] = s;
  __syncthreads();
  if (t == 0) bsum[blockIdx.x] = wsum[0] + wsum[1] + wsum[2] + wsum[3];
}

__global__ void scan_b(const int* __restrict__ bsum, int* __restrict__ bbase)
{
  int lane = threadIdx.x;                         // 64 threads
  int v[4]; int s = 0;
#pragma unroll
  for (int i = 0; i < 4; ++i) {
    int idx = lane * 4 + i;
    v[i] = (idx < NSB) ? bsum[idx] : 0; s += v[i];
  }
  int inc = s;
  for (int d = 1; d < 64; d <<= 1) {
    int o = __shfl_up(inc, d, 64);
    if (lane >= d) inc += o;
  }
  int running = inc - s;
#pragma unroll
  for (int i = 0; i < 4; ++i) {
    int idx = lane * 4 + i;
    if (idx < NSB) { bbase[idx] = running; running += v[i]; }
  }
}

__global__ __launch_bounds__(256) void scan_c(
    const int* __restrict__ cnt, const int* __restrict__ bbase,
    int* __restrict__ rowptr, int* __restrict__ rowfill)
{
  int t = threadIdx.x;
  int base = blockIdx.x * 4096 + t * 16;
  int v[16]; int s = 0;
#pragma unroll
  for (int i = 0; i < 16; ++i) {
    int idx = base + i;
    v[i] = (idx < NN) ? cnt[idx] : 0; s += v[i];
  }
  int lane = t & 63, wid = t >> 6;
  int inc = s;
  for (int d = 1; d < 64; d <<= 1) {
    int o = __shfl_up(inc, d, 64);
    if (lane >= d) inc += o;
  }
  __shared__ int wsum[4];
  if (lane == 63) wsum[wid] = inc;
  __syncthreads();
  int wb = 0;
  for (int w = 0; w < wid; ++w) wb += wsum[w];
  int running = bbase[blockIdx.x] + wb + (inc - s);
#pragma unroll
  for (int i = 0; i < 16; ++i) {
    int idx = base + i;
    if (idx < NN) { rowptr[idx] = running; rowfill[idx] = running; running += v[i]; }
  }
  if (blockIdx.x == 0 && t == 0) rowptr[NN] = EE;
}

__global__ __launch_bounds__(256) void place2(
    const int* __restrict__ ei, const int* __restrict__ et,
    const int* __restrict__ cntdr, int* __restrict__ rowfill,
    int2* __restrict__ recs)
{
  int e = blockIdx.x * 256 + threadIdx.x;
  int src = ei[e], dst = ei[EE + e], r = et[e];
  int slot = atomicAdd(&rowfill[dst], 1);
  float s = 1.0f / (float)max(cntdr[dst * RR + r], 1);
  int2 rec; rec.x = src | (r << 17); rec.y = __float_as_int(s);
  recs[slot] = rec;
}

// ---------------------------------------------------------------------------
// GEMM: Y[v][r][u-packed] = bf16( Xb[v] @ Wt[r] ), r=0..8. 64-row blocks.
// A-fragments register-resident across all 9 rounds; W double-buffered in LDS.
// Ypk uint u at (v*576 + r*64 + u): cols (32*(u>>4) + (u&15)) and +16.
// ---------------------------------------------------------------------------
__global__ __launch_bounds__(256, 2) void gemm_y(
    const unsigned int* __restrict__ Xb,     // [NN][64] uints (std bf16 rows)
    const unsigned short* __restrict__ Wt,   // [9][128][128] bf16 [r][n][k]
    unsigned int* __restrict__ Ypk)
{
  __shared__ unsigned short As[64 * 128];    // 16 KB
  __shared__ unsigned short Ws[2][128 * 128];// 64 KB
  const int tid = threadIdx.x;
  const int row0 = blockIdx.x * 64;
  const int wave = tid >> 6, lane = tid & 63;
  const int quad = lane >> 4, mr = lane & 15;

  // ---- stage A (rotated by (row&15)*8 shorts) ----
  {
    int row = tid >> 2, q = tid & 3, grow = row0 + row;
    const uint4v* xs = (const uint4v*)(Xb + (size_t)grow * 64 + q * 16);
#pragma unroll
    for (int c = 0; c < 4; ++c) {
      uint4v v = (grow < NN) ? xs[c] : (uint4v){0u, 0u, 0u, 0u};
      int pos = (q * 32 + c * 8 + (row & 15) * 8) & 127;
      *(uint4v*)&As[row * 128 + pos] = v;
    }
  }
  // ---- stage Ws[0] = relation 0 ----
  {
    int n = tid >> 1, half = tid & 1;
    const uint4v* wsrc = (const uint4v*)(Wt + (size_t)n * 128) + half * 8;
#pragma unroll
    for (int k = 0; k < 8; ++k) {
      uint4v v = wsrc[k];
      int pos = (half * 64 + k * 8 + (n & 15) * 8) & 127;
      *(uint4v*)&Ws[0][n * 128 + pos] = v;
    }
  }
  __syncthreads();

  // ---- A fragments: register-resident for all rounds ----
  short8 a[4];
  {
    int arow = wave * 16 + mr;
#pragma unroll
    for (int ks = 0; ks < 4; ++ks)
      a[ks] = *(const short8*)&As[arow * 128 + ((ks * 32 + quad * 8 + mr * 8) & 127)];
  }

  for (int r = 0; r < 9; ++r) {
    int cur = r & 1;
    // stage next W while computing on current
    if (r < 8) {
      int n = tid >> 1, half = tid & 1;
      const uint4v* wsrc = (const uint4v*)(Wt + ((size_t)(r + 1) * 128 + n) * 128) + half * 8;
#pragma unroll
      for (int k = 0; k < 8; ++k) {
        uint4v v = wsrc[k];
        int pos = (half * 64 + k * 8 + (n & 15) * 8) & 127;
        *(uint4v*)&Ws[1 - cur][n * 128 + pos] = v;
      }
    }

    floatx4 acc[8];
#pragma unroll
    for (int ni = 0; ni < 8; ++ni) acc[ni] = (floatx4){0.f, 0.f, 0.f, 0.f};
#pragma unroll
    for (int ks = 0; ks < 4; ++ks) {
#pragma unroll
      for (int ni = 0; ni < 8; ++ni) {
        short8 b = *(const short8*)&Ws[cur][(ni * 16 + mr) * 128 +
                                            ((ks * 32 + quad * 8 + mr * 8) & 127)];
        acc[ni] = __builtin_amdgcn_mfma_f32_16x16x32_bf16(a[ks], b, acc[ni], 0, 0, 0);
      }
    }
    // store packed col-pairs: uint u = nip*16+mr -> cols 32*nip+mr, +16
#pragma unroll
    for (int nip = 0; nip < 4; ++nip) {
#pragma unroll
      for (int rg = 0; rg < 4; ++rg) {
        int grow = row0 + wave * 16 + quad * 4 + rg;
        if (grow < NN)
          Ypk[(size_t)grow * 576 + r * 64 + nip * 16 + mr] =
              pk2bf(acc[2 * nip][rg], acc[2 * nip + 1][rg]);
      }
    }
    __syncthreads();
  }
}

// ---------------------------------------------------------------------------
// Aggregation: out[v] = relu(bias + Y8[v] + sum_e scale_e * Y_{r_e}[src_e]).
// 4 threads per dst row (quad shares edge list, 64 B contiguous each).
// No LDS, no barriers -> full occupancy; TLP hides gather latency.
// ---------------------------------------------------------------------------
__global__ __launch_bounds__(256) void aggregate(
    const unsigned int* __restrict__ Ypk,    // [NN][9][64]
    const int* __restrict__ rowptr,          // [NN+1]
    const int2* __restrict__ recs,           // [EE]
    const float* __restrict__ bias,          // [128]
    void* __restrict__ outp, int out_bf16)
{
  int gid = blockIdx.x * 256 + threadIdx.x;
  if (gid >= NN * 4) return;
  int v = gid >> 2, q = gid & 3;

  float lo[16], hi[16];
  // init: root (r=8) + bias
  {
    const uint4v* rp = (const uint4v*)(Ypk + (size_t)v * 576 + 8 * 64 + q * 16);
    uint4v u0 = rp[0], u1 = rp[1], u2 = rp[2], u3 = rp[3];
    unsigned um[16];
    *(uint4v*)&um[0] = u0; *(uint4v*)&um[4] = u1;
    *(uint4v*)&um[8] = u2; *(uint4v*)&um[12] = u3;
#pragma unroll
    for (int j = 0; j < 16; ++j) {
      lo[j] = bias[q * 32 + j] + bflo(um[j]);
      hi[j] = bias[q * 32 + 16 + j] + bfhi(um[j]);
    }
  }

  int beg = rowptr[v], end = rowptr[v + 1];
  int2 rec;
  if (beg < end) rec = recs[beg];
  for (int e = beg; e < end; ++e) {
    int2 nrec;
    if (e + 1 < end) nrec = recs[e + 1];
    int src = rec.x & 0x1FFFF;
    int r = ((unsigned)rec.x) >> 17;
    float s = __int_as_float(rec.y);
    const uint4v* yp = (const uint4v*)(Ypk + ((size_t)src * 9 + r) * 64 + q * 16);
    uint4v u0 = yp[0], u1 = yp[1], u2 = yp[2], u3 = yp[3];
    unsigned um[16];
    *(uint4v*)&um[0] = u0; *(uint4v*)&um[4] = u1;
    *(uint4v*)&um[8] = u2; *(uint4v*)&um[12] = u3;
#pragma unroll
    for (int j = 0; j < 16; ++j) {
      lo[j] = fmaf(s, bflo(um[j]), lo[j]);
      hi[j] = fmaf(s, bfhi(um[j]), hi[j]);
    }
    rec = nrec;
  }

#pragma unroll
  for (int j = 0; j < 16; ++j) {
    lo[j] = fmaxf(lo[j], 0.f);
    hi[j] = fmaxf(hi[j], 0.f);
  }

  if (out_bf16) {
    // bf16 std rows: uint t at col 32q+2t
    unsigned int* h = (unsigned int*)outp;
    uint4v w0, w1, w2, w3;
#pragma unroll
    for (int t = 0; t < 4; ++t) {
      w0[t] = pk2bf(lo[2 * t], lo[2 * t + 1]);
      w1[t] = pk2bf(lo[8 + 2 * t], lo[9 + 2 * t]);
      w2[t] = pk2bf(hi[2 * t], hi[2 * t + 1]);
      w3[t] = pk2bf(hi[8 + 2 * t], hi[9 + 2 * t]);
    }
    uint4v* d = (uint4v*)(h + (size_t)v * 64 + q * 16);
    d[0] = w0; d[1] = w1; d[2] = w2; d[3] = w3;
  } else {
    float* out = (float*)outp;
    float4* d = (float4*)(out + (size_t)v * 128 + q * 32);
#pragma unroll
    for (int t = 0; t < 4; ++t)
      d[t] = make_float4(lo[4 * t], lo[4 * t + 1], lo[4 * t + 2], lo[4 * t + 3]);
#pragma unroll
    for (int t = 0; t < 4; ++t)
      d[4 + t] = make_float4(hi[4 * t], hi[4 * t + 1], hi[4 * t + 2], hi[4 * t + 3]);
  }
}

// ---------------------------------------------------------------------------
extern "C" void kernel_launch(void* const* d_in, const int* in_sizes, int n_in,
                              void* d_out, int out_size, void* d_ws, size_t ws_size,
                              hipStream_t stream) {
  const float* x       = (const float*)d_in[0];
  const int*   ei      = (const int*)d_in[1];
  const int*   et      = (const int*)d_in[2];
  const float* rel_w1  = (const float*)d_in[3];
  const float* root_w1 = (const float*)d_in[4];
  const float* b1      = (const float*)d_in[5];
  const float* rel_w2  = (const float*)d_in[6];
  const float* root_w2 = (const float*)d_in[7];
  const float* b2      = (const float*)d_in[8];

  char* ws = (char*)d_ws;
  size_t off = 0;
  auto alloc = [&](size_t bytes) { char* p = ws + off; off = (off + bytes + 255) & ~(size_t)255; return p; };
  unsigned int*   Ypk   = (unsigned int*)alloc((size_t)NN * 576 * 4);    // 230.4 MB
  unsigned int*   Xbh   = (unsigned int*)alloc((size_t)NN * 64 * 4);     // 25.6 MB (Xb, then h1)
  unsigned short* Wt1   = (unsigned short*)alloc((size_t)9 * DD * DD * 2);
  unsigned short* Wt2   = (unsigned short*)alloc((size_t)9 * DD * DD * 2);
  int*            cntd  = (int*)alloc((size_t)NN * 4);
  int*            cntdr = (int*)alloc((size_t)NN * RR * 4);              // 3.2 MB
  int*            rowptr= (int*)alloc((size_t)(NN + 1) * 4);
  int*            rowfill=(int*)alloc((size_t)NN * 4);
  int2*           recs  = (int2*)alloc((size_t)EE * 8);                  // 5.12 MB
  int*            bsum  = (int*)alloc((size_t)NSB * 4);
  int*            bbase = (int*)alloc((size_t)NSB * 4);

  hipMemsetAsync(cntd, 0, (size_t)NN * 4, stream);
  hipMemsetAsync(cntdr, 0, (size_t)NN * RR * 4, stream);

  xb_prep<<<(NN * 16) / 256, 256, 0, stream>>>(x, Xbh);                  // 6250 blocks
  w_prep<<<(9 * DD * DD) / 256, 256, 0, stream>>>(rel_w1, root_w1, Wt1);
  w_prep<<<(9 * DD * DD) / 256, 256, 0, stream>>>(rel_w2, root_w2, Wt2);

  count2<<<EE / 256, 256, 0, stream>>>(ei, et, cntd, cntdr);
  scan_a<<<NSB, 256, 0, stream>>>((const int4*)cntd, bsum);
  scan_b<<<1, 64, 0, stream>>>(bsum, bbase);
  scan_c<<<NSB, 256, 0, stream>>>(cntd, bbase, rowptr, rowfill);
  place2<<<EE / 256, 256, 0, stream>>>(ei, et, cntdr, rowfill, recs);

  const int GB = (NN + 63) / 64;        // 1563
  const int AB = (NN * 4 + 255) / 256;  // 1563

  gemm_y<<<GB, 256, 0, stream>>>(Xbh, Wt1, Ypk);
  aggregate<<<AB, 256, 0, stream>>>(Ypk, rowptr, recs, b1, Xbh, 1);   // h1 over Xb
  gemm_y<<<GB, 256, 0, stream>>>(Xbh, Wt2, Ypk);
  aggregate<<<AB, 256, 0, stream>>>(Ypk, rowptr, recs, b2, d_out, 0);
}